// Round 1
// 304.831 us; speedup vs baseline: 1.4187x; 1.4187x over previous
//
#include <hip/hip_runtime.h>
#include <cmath>

// x[32768, 256] fp32, codebook[1024, 256] fp32. Outputs fp32 flat:
// loss(1), z_q(8388608), perplexity(1), indices(32768)
#define NROWS 32768
#define DDIM  256
#define KCB   1024

// Split-fp16 (hi+lo) path: dist error ~4e-5 sigma (fp32 MFMA accum + fp32
// rounding; dropped lo*lo term <= 8e-5 bounded). TAU=0.02 is ~500x that,
// vs the 27x ratio that validated TAU=0.35 on the pure-fp16 path.
// Flag rate ~1.2e-3 -> ~40 rows/32768 -> fp64 rescan is a correctness net
// that almost never executes.
constexpr float TAU = 0.02f;
constexpr int BSTR = 264;      // validated conflict-free stride (528 B/row)

typedef _Float16 half8 __attribute__((ext_vector_type(8)));
typedef _Float16 half4 __attribute__((ext_vector_type(4)));
typedef float floatx4 __attribute__((ext_vector_type(4)));

__global__ void init_kernel(double* __restrict__ sumsq, int* __restrict__ sumidx) {
  *sumsq = 0.0;
  *sumidx = 0;
}

// Exact codebook norms (fp64 -> fp32).
__global__ __launch_bounds__(64) void prep_kernel(const float* __restrict__ cb,
                                                  float* __restrict__ cn) {
  const int k = blockIdx.x, lane = threadIdx.x;
  float4 v = *(const float4*)(cb + (size_t)k * DDIM + lane * 4);
  double s = (double)v.x * v.x + (double)v.y * v.y
           + (double)v.z * v.z + (double)v.w * v.w;
  #pragma unroll
  for (int off = 32; off; off >>= 1) s += __shfl_down(s, off);
  if (lane == 0) cn[k] = (float)s;
}

// Block = 256 thr / 4 waves. Each wave owns 32 rows (two 16-row MFMA groups),
// A fragments held hi+lo in VGPRs -> every B-fragment read feeds 6 MFMAs.
// Stage = 32 codebook entries x 256 dims as {hi rows 0..31, lo rows 32..63}
// fp16 in the same 64xBSTR layout as the validated kernel; hi/lo computed
// on the fly from fp32 cb (same global bytes as an fp16 copy, no ws needed).
// dot = a_hi*b_hi + a_lo*b_hi + a_hi*b_lo  (3 MFMA into one fp32 acc).
// Pipeline per stage unchanged: write -> barrier -> issue loads(st+1) -> compute.
__global__ __launch_bounds__(256, 1) void fused_kernel(
    const float* __restrict__ x,
    const float* __restrict__ cb,
    const float* __restrict__ cn,
    float* __restrict__ zq_out,
    float* __restrict__ idx_out,
    double* __restrict__ sumsq,
    int* __restrict__ sumidx) {
  __shared__ __align__(16) _Float16 bs[2][64 * BSTR];  // 2 x 33 KB tiles
  __shared__ float cn_lds[KCB];
  __shared__ int   bidx[128];
  __shared__ float marg[128];
  __shared__ __align__(16) float xrow[DDIM];
  __shared__ int   flist[128];
  __shared__ int   nflag;
  __shared__ float wred[4];
  __shared__ double rv[4];
  __shared__ int    ri[4];

  const int tid = threadIdx.x;
  const int lane = tid & 63;
  const int w = tid >> 6;        // wave: rows w*32 .. +31
  const int q = lane >> 4;       // quad
  const int tx = lane & 15;
  const int row0 = blockIdx.x * 128;

  // ---- A fragments (hi+lo): lane holds x[row0+w*32+m*16+tx][s*32+q*8..+7] ----
  half8 a_hi[2][8], a_lo[2][8];
  #pragma unroll
  for (int m = 0; m < 2; ++m) {
    const float* xp = x + (size_t)(row0 + w * 32 + m * 16 + tx) * DDIM + q * 8;
    #pragma unroll
    for (int s = 0; s < 8; ++s) {
      float4 v0 = *(const float4*)(xp + s * 32);
      float4 v1 = *(const float4*)(xp + s * 32 + 4);
      half8 h, l;
      _Float16 t;
      t = (_Float16)v0.x; h[0] = t; l[0] = (_Float16)(v0.x - (float)t);
      t = (_Float16)v0.y; h[1] = t; l[1] = (_Float16)(v0.y - (float)t);
      t = (_Float16)v0.z; h[2] = t; l[2] = (_Float16)(v0.z - (float)t);
      t = (_Float16)v0.w; h[3] = t; l[3] = (_Float16)(v0.w - (float)t);
      t = (_Float16)v1.x; h[4] = t; l[4] = (_Float16)(v1.x - (float)t);
      t = (_Float16)v1.y; h[5] = t; l[5] = (_Float16)(v1.y - (float)t);
      t = (_Float16)v1.z; h[6] = t; l[6] = (_Float16)(v1.z - (float)t);
      t = (_Float16)v1.w; h[7] = t; l[7] = (_Float16)(v1.w - (float)t);
      a_hi[m][s] = h; a_lo[m][s] = l;
    }
  }
  #pragma unroll
  for (int i = 0; i < 4; ++i) cn_lds[tid + 256 * i] = cn[tid + 256 * i];
  if (tid == 0) nflag = 0;

  // stage ct covers entries ct*32..+31: 2048 float4 slots of fp32 cb;
  // slot = tid + 256*i -> entry e = slot>>6, float4-chunk c = slot&63
  float4 vld[8];
  auto load_stage = [&](int ct) {
    #pragma unroll
    for (int i = 0; i < 8; ++i) {
      int slot = tid + 256 * i;
      vld[i] = *(const float4*)(cb + (size_t)ct * 8192 + slot * 4);
    }
  };
  auto write_stage = [&](int buf) {
    #pragma unroll
    for (int i = 0; i < 8; ++i) {
      int slot = tid + 256 * i;
      int e = slot >> 6, c = slot & 63;
      float4 v = vld[i];
      half4 h, l;
      _Float16 t;
      t = (_Float16)v.x; h[0] = t; l[0] = (_Float16)(v.x - (float)t);
      t = (_Float16)v.y; h[1] = t; l[1] = (_Float16)(v.y - (float)t);
      t = (_Float16)v.z; h[2] = t; l[2] = (_Float16)(v.z - (float)t);
      t = (_Float16)v.w; h[3] = t; l[3] = (_Float16)(v.w - (float)t);
      *(half4*)&bs[buf][e * BSTR + c * 4] = h;         // hi rows 0..31
      *(half4*)&bs[buf][(32 + e) * BSTR + c * 4] = l;  // lo rows 32..63
    }
  };

  float minv[8], minv2[8];
  int mini[8];
  #pragma unroll
  for (int mi = 0; mi < 8; ++mi) { minv[mi] = INFINITY; minv2[mi] = INFINITY; mini[mi] = 0; }

  load_stage(0);
  for (int st = 0; st < 32; ++st) {
    const int buf = st & 1;
    write_stage(buf);            // consumes loads issued last iter (vmcnt wait)
    __syncthreads();             // tile visible; prev tile's readers done
    if (st + 1 < 32) load_stage(st + 1);   // in flight across compute(st)

    floatx4 acc[2][2];
    #pragma unroll
    for (int m = 0; m < 2; ++m)
      #pragma unroll
      for (int ci = 0; ci < 2; ++ci) acc[m][ci] = (floatx4){0.f, 0.f, 0.f, 0.f};

    #pragma unroll
    for (int s = 0; s < 8; ++s) {
      #pragma unroll
      for (int ci = 0; ci < 2; ++ci) {
        half8 bh = *(const half8*)&bs[buf][(ci * 16 + tx) * BSTR + (s * 4 + q) * 8];
        half8 bl = *(const half8*)&bs[buf][(32 + ci * 16 + tx) * BSTR + (s * 4 + q) * 8];
        #pragma unroll
        for (int m = 0; m < 2; ++m) {
          acc[m][ci] = __builtin_amdgcn_mfma_f32_16x16x32_f16(a_hi[m][s], bh, acc[m][ci], 0, 0, 0);
          acc[m][ci] = __builtin_amdgcn_mfma_f32_16x16x32_f16(a_lo[m][s], bh, acc[m][ci], 0, 0, 0);
          acc[m][ci] = __builtin_amdgcn_mfma_f32_16x16x32_f16(a_hi[m][s], bl, acc[m][ci], 0, 0, 0);
        }
      }
    }

    // epilogue: C/D layout col=lane&15, row=q*4+reg
    #pragma unroll
    for (int ci = 0; ci < 2; ++ci) {
      int col = st * 32 + ci * 16 + tx;
      float cnv = cn_lds[col];
      #pragma unroll
      for (int m = 0; m < 2; ++m) {
        #pragma unroll
        for (int r = 0; r < 4; ++r) {
          int mi = m * 4 + r;
          float dist = cnv - 2.f * acc[m][ci][r];
          if (dist < minv[mi]) {
            minv2[mi] = minv[mi];
            minv[mi] = dist; mini[mi] = col;
          } else if (dist < minv2[mi]) {
            minv2[mi] = dist;
          }
        }
      }
    }
  }

  // merge (best, idx, second) across the 16 tx-lanes of each quad
  #pragma unroll
  for (int off = 8; off; off >>= 1) {
    #pragma unroll
    for (int mi = 0; mi < 8; ++mi) {
      float ov  = __shfl_down(minv[mi],  off, 16);
      int   oi  = __shfl_down(mini[mi],  off, 16);
      float ov2 = __shfl_down(minv2[mi], off, 16);
      if (ov < minv[mi] || (ov == minv[mi] && oi < mini[mi])) {
        minv2[mi] = fminf(minv[mi], ov2);
        minv[mi] = ov; mini[mi] = oi;
      } else {
        minv2[mi] = fminf(minv2[mi], ov);
      }
    }
  }
  if (tx == 0) {
    #pragma unroll
    for (int m = 0; m < 2; ++m) {
      #pragma unroll
      for (int r = 0; r < 4; ++r) {
        int R = w * 32 + m * 16 + q * 4 + r;
        bidx[R] = mini[m * 4 + r];
        marg[R] = minv2[m * 4 + r] - minv[m * 4 + r];
      }
    }
  }
  __syncthreads();

  if (tid < 128 && marg[tid] < TAU) {
    int p = atomicAdd(&nflag, 1);
    flist[p] = tid;
  }
  __syncthreads();

  // exact fp64 re-scan of all 1024 candidates for flagged rows (~0.16/block)
  for (int f = 0; f < nflag; ++f) {
    int r = flist[f];
    if (tid < 64) {
      float4 v = *(const float4*)(x + (size_t)(row0 + r) * DDIM + tid * 4);
      xrow[tid * 4 + 0] = v.x; xrow[tid * 4 + 1] = v.y;
      xrow[tid * 4 + 2] = v.z; xrow[tid * 4 + 3] = v.w;
    }
    __syncthreads();
    double bestd = 1e300; int bi = 0;
    #pragma unroll
    for (int j = 0; j < 4; ++j) {
      int col = tid * 4 + j;
      const float* crow = cb + (size_t)col * DDIM;
      double s = 0.0;
      for (int d = 0; d < DDIM; d += 4) {
        float4 cv = *(const float4*)(crow + d);
        double d0 = (double)xrow[d + 0] - (double)cv.x; s = fma(d0, d0, s);
        double d1 = (double)xrow[d + 1] - (double)cv.y; s = fma(d1, d1, s);
        double d2 = (double)xrow[d + 2] - (double)cv.z; s = fma(d2, d2, s);
        double d3 = (double)xrow[d + 3] - (double)cv.w; s = fma(d3, d3, s);
      }
      if (s < bestd) { bestd = s; bi = col; }
    }
    #pragma unroll
    for (int off = 32; off; off >>= 1) {
      double ov = __shfl_down(bestd, off);
      int oi = __shfl_down(bi, off);
      if (ov < bestd || (ov == bestd && oi < bi)) { bestd = ov; bi = oi; }
    }
    if (lane == 0) { rv[w] = bestd; ri[w] = bi; }
    __syncthreads();
    if (tid == 0) {
      double bv = rv[0]; int bix = ri[0];
      for (int ww = 1; ww < 4; ++ww)
        if (rv[ww] < bv || (rv[ww] == bv && ri[ww] < bix)) { bv = rv[ww]; bix = ri[ww]; }
      bidx[r] = bix;
    }
    __syncthreads();
  }

  if (tid < 128) idx_out[row0 + tid] = (float)bidx[tid];

  // ---- gather: z_q rows (exact fp32 copies) + loss partial ----
  float lsum = 0.f;
  #pragma unroll 4
  for (int it = 0; it < 32; ++it) {
    int g = tid + 256 * it;        // 8192 float4 groups = 128 rows x 64 groups
    int r = g >> 6;
    int c4 = (g & 63) << 2;
    int k = bidx[r] & (KCB - 1);
    float4 cv = *(const float4*)(cb + (size_t)k * DDIM + c4);
    float4 xv = *(const float4*)(x + (size_t)(row0 + r) * DDIM + c4);
    float d0 = cv.x - xv.x, d1 = cv.y - xv.y, d2 = cv.z - xv.z, d3 = cv.w - xv.w;
    lsum = fmaf(d0, d0, lsum); lsum = fmaf(d1, d1, lsum);
    lsum = fmaf(d2, d2, lsum); lsum = fmaf(d3, d3, lsum);
    *(float4*)(zq_out + (size_t)(row0 + r) * DDIM + c4) = cv;
  }
  #pragma unroll
  for (int off = 32; off; off >>= 1) lsum += __shfl_down(lsum, off);
  if (lane == 0) wred[w] = lsum;
  __syncthreads();
  if (tid == 0) {
    atomicAdd(sumsq, (double)wred[0] + (double)wred[1] + (double)wred[2] + (double)wred[3]);
    int si = 0;
    #pragma unroll 8
    for (int r = 0; r < 128; ++r) si += bidx[r] & (KCB - 1);
    atomicAdd(sumidx, si);
  }
}

__global__ void finalize_kernel(const double* __restrict__ sumsq,
                                const int* __restrict__ sumidx,
                                float* __restrict__ out_loss,
                                float* __restrict__ out_perp) {
  // loss = mean(sg(zq)-x)^2 + 0.25*mean(zq-sg(x))^2 = 1.25 * MSE (fwd equal)
  double loss = 1.25 * (*sumsq) / 8388608.0;
  double e_min = (double)(*sumidx) / 32768.0;      // scalar mean of indices
  double perp = exp(-e_min * log(e_min + 1e-10));  // underflows to 0
  *out_loss = (float)loss;
  *out_perp = (float)perp;
}

extern "C" void kernel_launch(void* const* d_in, const int* in_sizes, int n_in,
                              void* d_out, int out_size, void* d_ws, size_t ws_size,
                              hipStream_t stream) {
  const float* x  = (const float*)d_in[0];   // [32768, 256] fp32
  const float* cb = (const float*)d_in[1];   // [1024, 256] fp32
  float* out = (float*)d_out;
  float* out_loss = out;                  // [0]
  float* out_zq   = out + 1;              // [1 .. 8388608]
  float* out_perp = out + 1 + 8388608;    // [8388609]
  float* out_idx  = out + 2 + 8388608;    // [8388610 ..]

  double*   sumsq  = (double*)d_ws;
  int*      sumidx = (int*)((char*)d_ws + 8);
  float*    cn     = (float*)((char*)d_ws + 16);      // 4 KB

  hipLaunchKernelGGL(init_kernel, dim3(1), dim3(1), 0, stream, sumsq, sumidx);
  hipLaunchKernelGGL(prep_kernel, dim3(KCB), dim3(64), 0, stream, cb, cn);
  hipLaunchKernelGGL(fused_kernel, dim3(NROWS / 128), dim3(256), 0, stream,
                     x, cb, cn, out_zq, out_idx, sumsq, sumidx);
  hipLaunchKernelGGL(finalize_kernel, dim3(1), dim3(1), 0, stream,
                     sumsq, sumidx, out_loss, out_perp);
}